// Round 14
// baseline (334.322 us; speedup 1.0000x reference)
//
#include <hip/hip_runtime.h>

typedef unsigned short u16;
typedef __attribute__((ext_vector_type(8))) short bf16x8;
typedef __attribute__((ext_vector_type(8))) unsigned short u16x8;
typedef __attribute__((ext_vector_type(4))) float f32x4;

#define L_SEQ 2048
#define NTOK 4096   // B*L
#define DMODEL 1024
#define DEXP 2048
#define NH 16
#define DH 128

__device__ __forceinline__ u16 f2bf(float f) {
    unsigned u = __float_as_uint(f);
    unsigned r = (u + 0x7FFFu + ((u >> 16) & 1u)) >> 16;
    return (u16)r;
}
__device__ __forceinline__ float bf2f(u16 h) {
    return __uint_as_float(((unsigned)h) << 16);
}

// async global->LDS, 16B per lane; LDS dest = wave-uniform base + lane*16
__device__ __forceinline__ void gl_lds16(const u16* g, u16* l) {
    __builtin_amdgcn_global_load_lds((const __attribute__((address_space(1))) void*)g,
                                     (__attribute__((address_space(3))) void*)l, 16, 0, 0);
}

// ---------------- convert + transpose fp32 -> bf16, out[c*R + r] = in[r*C + c]
__global__ void conv_transpose(const float* __restrict__ in, u16* __restrict__ out, int R, int C) {
    __shared__ unsigned tile[32][33];
    int c0 = blockIdx.x * 32, r0 = blockIdx.y * 32;
    int tx = threadIdx.x, ty = threadIdx.y;
    for (int j = 0; j < 32; j += 8)
        tile[ty + j][tx] = (unsigned)f2bf(in[(size_t)(r0 + ty + j) * C + c0 + tx]);
    __syncthreads();
    for (int j = 0; j < 32; j += 8)
        out[(size_t)(c0 + ty + j) * R + r0 + tx] = (u16)tile[tx][ty + j];
}

// ---------------- layernorm over 1024, out bf16 or fp32
__global__ __launch_bounds__(256) void ln_fwd(const float* __restrict__ x, const float* __restrict__ g,
                                              const float* __restrict__ bta, void* __restrict__ outp,
                                              int out_bf16) {
    int row = blockIdx.x;
    int t = threadIdx.x;
    const float* xr = x + (size_t)row * DMODEL;
    float4 xv = *(const float4*)&xr[t * 4];
    float s = xv.x + xv.y + xv.z + xv.w;
    float s2 = xv.x * xv.x + xv.y * xv.y + xv.z * xv.z + xv.w * xv.w;
    for (int off = 32; off >= 1; off >>= 1) {
        s += __shfl_xor(s, off);
        s2 += __shfl_xor(s2, off);
    }
    __shared__ float red[10];
    int w = t >> 6;
    if ((t & 63) == 0) { red[w] = s; red[4 + w] = s2; }
    __syncthreads();
    if (t == 0) {
        red[8] = red[0] + red[1] + red[2] + red[3];
        red[9] = red[4] + red[5] + red[6] + red[7];
    }
    __syncthreads();
    float mu = red[8] * (1.0f / DMODEL);
    float var = red[9] * (1.0f / DMODEL) - mu * mu;
    float rstd = rsqrtf(var + 1e-5f);
    float vals[4] = {xv.x, xv.y, xv.z, xv.w};
    for (int e = 0; e < 4; e++) {
        int c = t * 4 + e;
        float y = (vals[e] - mu) * rstd * g[c] + bta[c];
        if (out_bf16) ((u16*)outp)[(size_t)row * DMODEL + c] = f2bf(y);
        else          ((float*)outp)[(size_t)row * DMODEL + c] = y;
    }
}

// ---------------- GEMM1: 256x256 tile, BK=64, 8 waves, 8-phase zigzag schedule
// with operand-register reuse (r12, verified: ~83 us / absmax 0.03125).
__global__ __launch_bounds__(512, 2) void gemm_8ph(const u16* __restrict__ A, const u16* __restrict__ BT,
                                                   u16* __restrict__ C, int M, int N, int K) {
    __shared__ u16 a_s[32768];   // [buf2][half2][row128][seg8][8]
    __shared__ u16 b_s[32768];
    int tid = threadIdx.x;
    int w = tid >> 6, lane = tid & 63, quad = lane >> 4, ln = lane & 15;
    int lsw = ln & 7;
    int awrow = (w >> 2) * 64 + ln;   // wave row base within A-half (+fr*16)
    int bwcol = (w & 3) * 32 + ln;    // wave col base within B-half (+fc*16)

    unsigned lin = blockIdx.x + gridDim.x * blockIdx.y;   // gridDim.x = N/256
    unsigned per = gridDim.x >> 3;
    unsigned xcd = lin & 7, tt = lin >> 3;
    unsigned n_p = xcd * per + (tt % per);
    unsigned m_p = tt / per;
    int m0 = m_p * 256, n0 = n_p * 256;

    const u16 *Ah0[2], *Ah1[2], *Bh0[2], *Bh1[2];
    int ldoff[2];
#pragma unroll
    for (int j = 0; j < 2; j++) {
        int s = j * 512 + tid;
        int row = s >> 3, seg = s & 7;
        int sw = seg ^ (row & 7);
        Ah0[j] = A + (size_t)(m0 + row) * K + sw * 8;
        Ah1[j] = A + (size_t)(m0 + 128 + row) * K + sw * 8;
        Bh0[j] = BT + (size_t)(n0 + row) * K + sw * 8;
        Bh1[j] = BT + (size_t)(n0 + 128 + row) * K + sw * 8;
        ldoff[j] = (j * 512 + w * 64) * 8;
    }

    f32x4 zero4 = {0.f, 0.f, 0.f, 0.f};
    f32x4 acc[4][4][2];   // [quadrant QM*2+QN][fr][fc]
#pragma unroll
    for (int q = 0; q < 4; q++)
#pragma unroll
        for (int fr = 0; fr < 4; fr++)
#pragma unroll
            for (int fc = 0; fc < 2; fc++) acc[q][fr][fc] = zero4;

    bf16x8 af_[4][2], bf_[2][2];   // live across phases (zigzag reuse)

#define G1_STAGE(MS, PTRS, B, H, T)                                                   \
    do {                                                                              \
        _Pragma("unroll") for (int j = 0; j < 2; j++)                                 \
            gl_lds16(PTRS[j] + (size_t)(T) * 64, &MS[((B)*2 + (H)) * 8192 + ldoff[j]]); \
    } while (0)

#define G1_PHASE(BUF, QM, QN, DOA, DOB, STAGE_STMT, TAILGATE)                         \
    do {                                                                              \
        if (DOA) {                                                                    \
            _Pragma("unroll") for (int fr = 0; fr < 4; fr++)                          \
            _Pragma("unroll") for (int ks = 0; ks < 2; ks++)                          \
                af_[fr][ks] = *(const bf16x8*)&a_s[((BUF)*2 + (QM)) * 8192 +          \
                    (awrow + fr * 16) * 64 + (((ks * 4 + quad) ^ lsw) * 8)];          \
        }                                                                             \
        if (DOB) {                                                                    \
            _Pragma("unroll") for (int fc = 0; fc < 2; fc++)                          \
            _Pragma("unroll") for (int ks = 0; ks < 2; ks++)                          \
                bf_[fc][ks] = *(const bf16x8*)&b_s[((BUF)*2 + (QN)) * 8192 +          \
                    (bwcol + fc * 16) * 64 + (((ks * 4 + quad) ^ lsw) * 8)];          \
        }                                                                             \
        STAGE_STMT;                                                                   \
        __builtin_amdgcn_s_barrier();                                                 \
        asm volatile("s_waitcnt lgkmcnt(0)" ::: "memory");                            \
        __builtin_amdgcn_sched_barrier(0);                                            \
        __builtin_amdgcn_s_setprio(1);                                                \
        _Pragma("unroll") for (int fr = 0; fr < 4; fr++)                              \
        _Pragma("unroll") for (int fc = 0; fc < 2; fc++)                              \
        _Pragma("unroll") for (int ks = 0; ks < 2; ks++)                              \
            acc[(QM)*2 + (QN)][fr][fc] = __builtin_amdgcn_mfma_f32_16x16x32_bf16(     \
                af_[fr][ks], bf_[fc][ks], acc[(QM)*2 + (QN)][fr][fc], 0, 0, 0);       \
        __builtin_amdgcn_s_setprio(0);                                                \
        TAILGATE;                                                                     \
        __builtin_amdgcn_s_barrier();                                                 \
    } while (0)

    int NT = K >> 6;   // 16

    G1_STAGE(a_s, Ah0, 0, 0, 0);
    G1_STAGE(a_s, Ah1, 0, 1, 0);
    G1_STAGE(b_s, Bh0, 0, 0, 0);
    G1_STAGE(b_s, Bh1, 0, 1, 0);
    G1_STAGE(a_s, Ah0, 1, 0, 1);
    G1_STAGE(b_s, Bh1, 1, 1, 1);
    asm volatile("s_waitcnt vmcnt(4)" ::: "memory");
    __builtin_amdgcn_s_barrier();

    for (int t = 0; t < NT; t++) {
        int buf = t & 1, nb = buf ^ 1;
        G1_PHASE(buf, 0, 0, 1, 1, { if (t + 1 < NT) G1_STAGE(a_s, Ah1, nb, 1, t + 1); }, {});
        G1_PHASE(buf, 0, 1, 0, 1, { if (t + 1 < NT) G1_STAGE(b_s, Bh0, nb, 0, t + 1); }, {});
        G1_PHASE(buf, 1, 1, 1, 0, { if (t + 2 < NT) G1_STAGE(a_s, Ah0, buf, 0, t + 2); }, {});
        G1_PHASE(buf, 1, 0, 0, 1, { if (t + 2 < NT) G1_STAGE(b_s, Bh1, buf, 1, t + 2); },
                 {
                     if (t + 2 < NT) asm volatile("s_waitcnt vmcnt(4)" ::: "memory");
                     else            asm volatile("s_waitcnt vmcnt(0)" ::: "memory");
                 });
    }

#undef G1_STAGE
#undef G1_PHASE

#pragma unroll
    for (int QM = 0; QM < 2; QM++)
#pragma unroll
        for (int QN = 0; QN < 2; QN++)
#pragma unroll
            for (int fr = 0; fr < 4; fr++)
#pragma unroll
                for (int fc = 0; fc < 2; fc++)
#pragma unroll
                    for (int e = 0; e < 4; e++) {
                        int row = m0 + QM * 128 + (w >> 2) * 64 + fr * 16 + quad * 4 + e;
                        int col = n0 + QN * 128 + (w & 3) * 32 + fc * 16 + ln;
                        C[(size_t)row * N + col] = f2bf(acc[QM * 2 + QN][fr][fc][e]);
                    }
}

// ---------------- GEMM2: 64x128 tile, BK=64 (r13, verified). 512 blocks =
// 2 blocks/CU; LDS 48KB dbuf; 3-bit seg-XOR swizzle.
__global__ __launch_bounds__(256) void gemm_bt64(const u16* __restrict__ A, const u16* __restrict__ BT,
                                                 float* __restrict__ C, int M, int N, int K) {
    __shared__ u16 a_s[2][4096];   // dbuf x [row64][seg8][8]
    __shared__ u16 b_s[2][8192];   // dbuf x [row128][seg8][8]
    int tid = threadIdx.x;
    unsigned NX = gridDim.x;       // N/128 = 8
    unsigned lin = blockIdx.x + NX * blockIdx.y;
    unsigned per = NX >> 3;
    unsigned xcd = lin & 7, t = lin >> 3;
    unsigned n_p = xcd * per + (t % per);
    unsigned m_p = t / per;
    int m0 = m_p * 64, n0 = n_p * 128;
    int w = tid >> 6, lane = tid & 63, quad = lane >> 4, ln = lane & 15;
    int wc = w * 32, lsw = ln & 7;
    f32x4 zero4 = {0.f, 0.f, 0.f, 0.f};
    f32x4 acc[4][2];
    for (int r = 0; r < 4; r++)
        for (int c = 0; c < 2; c++) acc[r][c] = zero4;

    const u16* Ag[2];
    int aoff[2];
#pragma unroll
    for (int j = 0; j < 2; j++) {
        int s = j * 256 + tid;
        int row = s >> 3, seg = s & 7;
        Ag[j] = A + (size_t)(m0 + row) * K + (seg ^ (row & 7)) * 8;
        aoff[j] = s * 8;
    }
    const u16* Bg[4];
    int boff[4];
#pragma unroll
    for (int j = 0; j < 4; j++) {
        int s = j * 256 + tid;
        int row = s >> 3, seg = s & 7;
        Bg[j] = BT + (size_t)(n0 + row) * K + (seg ^ (row & 7)) * 8;
        boff[j] = s * 8;
    }

    for (int j = 0; j < 2; j++) gl_lds16(Ag[j], &a_s[0][aoff[j]]);
    for (int j = 0; j < 4; j++) gl_lds16(Bg[j], &b_s[0][boff[j]]);
    __syncthreads();

    int cur = 0;
    for (int k0 = 0; k0 < K; k0 += 64) {
        if (k0 + 64 < K) {
            int nb = cur ^ 1;
            for (int j = 0; j < 2; j++) gl_lds16(Ag[j] + k0 + 64, &a_s[nb][aoff[j]]);
            for (int j = 0; j < 4; j++) gl_lds16(Bg[j] + k0 + 64, &b_s[nb][boff[j]]);
        }
        bf16x8 af[4][2], bfr[2][2];
#pragma unroll
        for (int r = 0; r < 4; r++)
#pragma unroll
            for (int ks = 0; ks < 2; ks++)
                af[r][ks] = *(const bf16x8*)&a_s[cur][(r * 16 + ln) * 64 + (((ks * 4 + quad) ^ lsw) * 8)];
#pragma unroll
        for (int c = 0; c < 2; c++)
#pragma unroll
            for (int ks = 0; ks < 2; ks++)
                bfr[c][ks] = *(const bf16x8*)&b_s[cur][(wc + c * 16 + ln) * 64 + (((ks * 4 + quad) ^ lsw) * 8)];
        __builtin_amdgcn_s_setprio(1);
#pragma unroll
        for (int r = 0; r < 4; r++)
#pragma unroll
            for (int c = 0; c < 2; c++)
#pragma unroll
                for (int ks = 0; ks < 2; ks++)
                    acc[r][c] = __builtin_amdgcn_mfma_f32_16x16x32_bf16(af[r][ks], bfr[c][ks], acc[r][c], 0, 0, 0);
        __builtin_amdgcn_s_setprio(0);
        __syncthreads();
        cur ^= 1;
    }
    for (int r = 0; r < 4; r++)
        for (int c = 0; c < 2; c++)
            for (int e = 0; e < 4; e++) {
                int row = m0 + r * 16 + quad * 4 + e;
                int col = n0 + wc + c * 16 + ln;
                C[(size_t)row * N + col] = acc[r][c][e];
            }
}

// ---------------- fused per-(b,h) V-transpose + K-smear (r13, verified)
__global__ void vT_smear(const u16* __restrict__ qkvp, const float* __restrict__ smear_f,
                         u16* __restrict__ v_t, u16* __restrict__ k_sm) {
    __shared__ unsigned tile[32][33];
    int bh = blockIdx.z;
    int bb = bh >> 4, h = bh & 15;
    int tx = threadIdx.x, ty = threadIdx.y;
    size_t tokb = (size_t)bb * L_SEQ;
    if (blockIdx.y < 4) {
        int l0 = blockIdx.x * 32, d0 = blockIdx.y * 32;
        for (int j = 0; j < 32; j += 8)
            tile[ty + j][tx] = (unsigned)qkvp[(tokb + l0 + ty + j) * 8192 + 4096 + h * DH + d0 + tx];
        __syncthreads();
        for (int j = 0; j < 32; j += 8)
            v_t[((size_t)bh * DH + d0 + ty + j) * L_SEQ + l0 + tx] = (u16)tile[tx][ty + j];
    } else {
        int l0 = blockIdx.x * 32;
        int tid = ty * 32 + tx;
        float s = 1.0f / (1.0f + __expf(-smear_f[h]));
        for (int p = 0; p < 2; p++) {
            int v = tid + p * 256;       // 0..511
            int lr = v >> 4;             // 0..31
            int d = (v & 15) * 8;
            int l = l0 + lr;
            u16x8 cur = *(const u16x8*)&qkvp[(tokb + l) * 8192 + 2048 + h * DH + d];
            u16x8 prv = {0, 0, 0, 0, 0, 0, 0, 0};
            if (l > 0) prv = *(const u16x8*)&qkvp[(tokb + l - 1) * 8192 + 2048 + h * DH + d];
            u16x8 outv;
            for (int u = 0; u < 8; u++) {
                float kc = bf2f(cur[u]);
                float kp = bf2f(prv[u]);
                outv[u] = f2bf((1.0f - s) * kc + s * kp);
            }
            *(u16x8*)&k_sm[(((size_t)bh) * L_SEQ + l) * DH + d] = outv;
        }
    }
}

// ---------------- flash attention + SiLU(p) gating
// Round-14: 4 independent contexts/CU. 32-row strips (64 strips/bh), balanced
// pairs (63-p, p) = 33 iters/block; grid 1024, block 128 (2 waves x 16 rows).
// LDS single-buffered: K 16KB + V 16KB + P 4.6KB = 37376 B -> 4 blocks/CU
// (precedent: r4's 74752 x 2 = same 149504 B total fits). Same 8 waves/CU as
// before but 4 barrier-decoupled contexts: one block's stage-drain stall
// overlaps three other blocks' compute (was 2 contexts, heavy convoying).
// All arithmetic byte-identical to r12 -> absmax must stay 0.03125.
__global__ __launch_bounds__(128) void attn_kernel(const u16* __restrict__ qkvp,
                                                   const u16* __restrict__ k_sm,
                                                   const u16* __restrict__ v_t,
                                                   u16* __restrict__ ag2,
                                                   const float* __restrict__ log_scale) {
    __shared__ u16 k_s[8192];    // [cgi 0..3][g 0..3][16 rows][8 seg][8] (swizzled content)
    __shared__ u16 vt_s[8192];   // [jt 0..1][dg 0..7][16 rows][8 seg][8]
    __shared__ u16 p_s[2304];    // 2 waves x 16 x 72
    int tid = threadIdx.x;
    // XCD clustering: lin%8 = XCD; 4 heads per XCD; pair index 0..31.
    unsigned lin = blockIdx.x + 32u * blockIdx.y;
    unsigned xcd = lin & 7, tt = lin >> 3;
    int bh = (int)(xcd * 4 + (tt & 3));
    int pr = (int)(tt >> 2);            // 0..31
    int bb = bh >> 4, h = bh & 15;
    int w = tid >> 6, lane = tid & 63, quad = lane >> 4, ln = lane & 15;
    size_t tokb = (size_t)bb * L_SEQ;

    const float LOG2E = 1.44269504f;
    float inv = 1.0f / (__expf(2.0f * log_scale[h]) * sqrtf((float)DH));
    float scl = inv * LOG2E;
    float slope2 = ((h < 8) ? exp2f(-8.0f * (float)h / 7.0f) : 0.0f) * LOG2E;

    int lrow = lane >> 2, lcol = lane & 3;
    int lsw8 = (lcol ^ ((lrow >> 1) & 3)) * 8;  // write-side swizzle via global source addr
    int qsw = (quad ^ ((ln >> 1) & 3)) * 8;     // read-side swizzle (same involution)
    f32x4 zero4 = {0.f, 0.f, 0.f, 0.f};
    u16* pw = &p_s[w * 1152];
    const short ONE_BF = (short)0x3F80;
    bf16x8 ones = {ONE_BF, ONE_BF, ONE_BF, ONE_BF, ONE_BF, ONE_BF, ONE_BF, ONE_BF};

    for (int sidx = 0; sidx < 2; sidx++) {
        int ib = sidx == 0 ? (63 - pr) : pr;    // 32-row strip index 0..63
        int i0 = ib * 32;
        int si = i0 + w * 16;
        int iq = si + ln;          // this lane's q-row (swapped layout)

        // Q fragments straight from global
        bf16x8 qf[4];
        for (int kt = 0; kt < 4; kt++)
            qf[kt] = *(const bf16x8*)&qkvp[(tokb + si + ln) * 8192 + h * DH + kt * 32 + quad * 8];

        // shifted-domain running max
        float mshift = -1e30f;
        float astep = slope2 * 64.0f;
        f32x4 o_acc[8], l_acc;
        for (int dt = 0; dt < 8; dt++) o_acc[dt] = zero4;
        l_acc = zero4;

        float adt0[4][4];
        for (int ct = 0; ct < 4; ct++)
            for (int r = 0; r < 4; r++)
                adt0[ct][r] = slope2 * (float)(ct * 16 + quad * 4 + r);

        // staging: wave w covers col-groups {2w, 2w+1} of K and c = w*8+q of V
        const u16* kg[8];
        int kloff[8];
        for (int g = 0; g < 4; g++)
            for (int cg = 0; cg < 2; cg++) {
                int cgi = w * 2 + cg;
                kg[g * 2 + cg] = k_sm + ((size_t)bh * L_SEQ + g * 16 + lrow) * DH + cgi * 32 + lsw8;
                kloff[g * 2 + cg] = cgi * 2048 + g * 512;
            }
        const u16* vg[8];
        int vloff[8];
        for (int q = 0; q < 8; q++) {
            int c = w * 8 + q;
            int jt = c >> 3, dg = c & 7;
            vg[q] = v_t + ((size_t)bh * DH + dg * 16 + lrow) * L_SEQ + jt * 32 + lsw8;
            vloff[q] = jt * 4096 + dg * 512;
        }

        for (int j0 = 0; j0 <= i0 + 31; j0 += 64) {
            __syncthreads();   // previous iter's LDS reads complete before restage
            for (int g = 0; g < 8; g++) { gl_lds16(kg[g], &k_s[kloff[g]]); kg[g] += 64 * DH; }
            for (int q = 0; q < 8; q++) { gl_lds16(vg[q], &vt_s[vloff[q]]); vg[q] += 64; }
            __syncthreads();   // drains vmcnt: tiles resident

            // S^T = K Q^T: swapped operands. sc[ct][r] = S[si+ln][j0 + ct*16 + quad*4 + r]
            f32x4 sc[4];
            for (int ct = 0; ct < 4; ct++) sc[ct] = zero4;
            __builtin_amdgcn_s_setprio(1);
            for (int kt = 0; kt < 4; kt++)
                for (int ct = 0; ct < 4; ct++) {
                    bf16x8 bfr = *(const bf16x8*)&k_s[kt * 2048 + (ct * 16 + ln) * 32 + qsw];
                    sc[ct] = __builtin_amdgcn_mfma_f32_16x16x32_bf16(bfr, qf[kt], sc[ct], 0, 0, 0);
                }
            __builtin_amdgcn_s_setprio(0);

            bool full = (j0 + 63 <= si);
            float s2[4][4];
            for (int ct = 0; ct < 4; ct++)
                for (int r = 0; r < 4; r++) {
                    float v = fmaf(sc[ct][r], scl, adt0[ct][r]);
                    if (!full) {
                        int j = j0 + ct * 16 + quad * 4 + r;
                        if (j > iq) v = -3.0e38f;
                    }
                    s2[ct][r] = v;
                }
            // row max in shifted domain: max3-shaped tree + cross-quad reduce
            float x0 = fmaxf(fmaxf(s2[0][0], s2[0][1]), s2[0][2]);
            float x1 = fmaxf(fmaxf(s2[0][3], s2[1][0]), s2[1][1]);
            float x2 = fmaxf(fmaxf(s2[1][2], s2[1][3]), s2[2][0]);
            float x3 = fmaxf(fmaxf(s2[2][1], s2[2][2]), s2[2][3]);
            float x4 = fmaxf(fmaxf(s2[3][0], s2[3][1]), s2[3][2]);
            float y0 = fmaxf(fmaxf(x0, x1), x2);
            float y1 = fmaxf(fmaxf(x3, x4), s2[3][3]);
            float mr = fmaxf(y0, y1);
            mr = fmaxf(mr, __shfl_xor(mr, 16));
            mr = fmaxf(mr, __shfl_xor(mr, 32));
            float msh_old = mshift - astep;
            float mnew = fmaxf(msh_old, mr);
            float alpha = exp2f(msh_old - mnew);
            mshift = mnew;

            // P: exp2 in shifted domain, v_perm pack, 4x ds_write_b64
            for (int ct = 0; ct < 4; ct++) {
                float p0 = exp2f(s2[ct][0] - mnew);
                float p1 = exp2f(s2[ct][1] - mnew);
                float p2 = exp2f(s2[ct][2] - mnew);
                float p3 = exp2f(s2[ct][3] - mnew);
                unsigned d0 = __builtin_amdgcn_perm(__float_as_uint(p1), __float_as_uint(p0), 0x07060302u);
                unsigned d1 = __builtin_amdgcn_perm(__float_as_uint(p3), __float_as_uint(p2), 0x07060302u);
                uint2 dd; dd.x = d0; dd.y = d1;
                *(uint2*)&pw[ln * 72 + ct * 16 + quad * 4] = dd;
            }

            // rescale O/l: gather alpha for rows quad*4+e from lanes (quad*16)+(quad*4+e)
            if (__any(alpha != 1.0f)) {
                float av[4];
                for (int e = 0; e < 4; e++) av[e] = __shfl(alpha, quad * 20 + e);
                for (int dt = 0; dt < 8; dt++) {
                    f32x4 o = o_acc[dt];
                    for (int e = 0; e < 4; e++) o[e] *= av[e];
                    o_acc[dt] = o;
                }
                for (int e = 0; e < 4; e++) l_acc[e] *= av[e];
            }
            asm volatile("s_waitcnt lgkmcnt(0)" ::: "memory");
            __builtin_amdgcn_s_setprio(1);
            for (int ks = 0; ks < 2; ks++) {
                bf16x8 pa = *(const bf16x8*)&pw[ln * 72 + ks * 32 + quad * 8];
                l_acc = __builtin_amdgcn_mfma_f32_16x16x32_bf16(pa, ones, l_acc, 0, 0, 0);
                for (int dt = 0; dt < 8; dt++) {
                    bf16x8 vf = *(const bf16x8*)&vt_s[ks * 4096 + (dt * 16 + ln) * 32 + qsw];
                    o_acc[dt] = __builtin_amdgcn_mfma_f32_16x16x32_bf16(pa, vf, o_acc[dt], 0, 0, 0);
                }
            }
            __builtin_amdgcn_s_setprio(0);
        }

        // epilogue: normalize (rcp), SiLU(p) gate (exp2+rcp), store bf16
        float rinv[4];
        for (int r = 0; r < 4; r++) rinv[r] = __builtin_amdgcn_rcpf(l_acc[r]);
        for (int dt = 0; dt < 8; dt++)
            for (int r = 0; r < 4; r++) {
                int i = si + quad * 4 + r;
                int dcol = dt * 16 + ln;
                float o = o_acc[dt][r] * rinv[r];
                float pv = bf2f(qkvp[(tokb + i) * 8192 + 6144 + h * DH + dcol]);
                float gate = pv * __builtin_amdgcn_rcpf(1.0f + exp2f(-pv * LOG2E));
                ag2[(tokb + i) * 2048 + h * DH + dcol] = f2bf(gate * o);
            }
    }
}

extern "C" void kernel_launch(void* const* d_in, const int* in_sizes, int n_in,
                              void* d_out, int out_size, void* d_ws, size_t ws_size,
                              hipStream_t stream) {
    const float* x       = (const float*)d_in[0];
    const float* ln1_g   = (const float*)d_in[1];
    const float* ln1_b   = (const float*)d_in[2];
    const float* ln2_g   = (const float*)d_in[3];
    const float* ln2_b   = (const float*)d_in[4];
    const float* w_in    = (const float*)d_in[5];
    const float* w_out   = (const float*)d_in[6];
    const float* smear_f = (const float*)d_in[7];
    const float* logsc   = (const float*)d_in[8];
    float* out = (float*)d_out;
    char* ws = (char*)d_ws;

    // ws layout (bytes)
    u16* w_inT   = (u16*)(ws + 0);                       // 16 MB  [8192,1024]
    u16* w_outT  = (u16*)(ws + (size_t)16777216);        //  4 MB  [1024,2048]
    u16* lnA     = (u16*)(ws + (size_t)20971520);        //  8 MB  [4096,1024]
    u16* qkvp    = (u16*)(ws + (size_t)29360128);        // 64 MB  [4096,8192]
    u16* k_sm    = (u16*)(ws + (size_t)96468992);        // 16 MB  [bh][l][128]
    u16* ag2     = (u16*)(ws + (size_t)113246208);       // 16 MB  [4096,2048]
    float* out_pre = (float*)(ws + (size_t)96468992);    // alias k_sm (dead after attn)
    u16* v_t     = (u16*)(ws + 0);                       // alias w_inT (dead after gemm1)

    dim3 b32x8(32, 8);
    conv_transpose<<<dim3(8192 / 32, 1024 / 32), b32x8, 0, stream>>>(w_in, w_inT, 1024, 8192);
    conv_transpose<<<dim3(1024 / 32, 2048 / 32), b32x8, 0, stream>>>(w_out, w_outT, 2048, 1024);
    ln_fwd<<<NTOK, 256, 0, stream>>>(x, ln1_g, ln1_b, (void*)lnA, 1);
    gemm_8ph<<<dim3(8192 / 256, 4096 / 256), 512, 0, stream>>>(lnA, w_inT, qkvp, NTOK, 8192, 1024);
    vT_smear<<<dim3(L_SEQ / 32, 5, 32), b32x8, 0, stream>>>(qkvp, smear_f, v_t, k_sm);
    attn_kernel<<<dim3(32, 32), 128, 0, stream>>>(qkvp, k_sm, v_t, ag2, logsc);
    gemm_bt64<<<dim3(1024 / 128, 4096 / 64), 256, 0, stream>>>(ag2, w_outT, out_pre, NTOK, 1024, 2048);
    ln_fwd<<<NTOK, 256, 0, stream>>>(out_pre, ln2_g, ln2_b, (void*)out, 0);
}

// Round 15
// 324.056 us; speedup vs baseline: 1.0317x; 1.0317x over previous
//
#include <hip/hip_runtime.h>

typedef unsigned short u16;
typedef __attribute__((ext_vector_type(8))) short bf16x8;
typedef __attribute__((ext_vector_type(8))) unsigned short u16x8;
typedef __attribute__((ext_vector_type(4))) float f32x4;

#define L_SEQ 2048
#define NTOK 4096   // B*L
#define DMODEL 1024
#define DEXP 2048
#define NH 16
#define DH 128

__device__ __forceinline__ u16 f2bf(float f) {
    unsigned u = __float_as_uint(f);
    unsigned r = (u + 0x7FFFu + ((u >> 16) & 1u)) >> 16;
    return (u16)r;
}
__device__ __forceinline__ float bf2f(u16 h) {
    return __uint_as_float(((unsigned)h) << 16);
}

// async global->LDS, 16B per lane; LDS dest = wave-uniform base + lane*16
__device__ __forceinline__ void gl_lds16(const u16* g, u16* l) {
    __builtin_amdgcn_global_load_lds((const __attribute__((address_space(1))) void*)g,
                                     (__attribute__((address_space(3))) void*)l, 16, 0, 0);
}

// ---------------- convert + transpose fp32 -> bf16, out[c*R + r] = in[r*C + c]
__global__ void conv_transpose(const float* __restrict__ in, u16* __restrict__ out, int R, int C) {
    __shared__ unsigned tile[32][33];
    int c0 = blockIdx.x * 32, r0 = blockIdx.y * 32;
    int tx = threadIdx.x, ty = threadIdx.y;
    for (int j = 0; j < 32; j += 8)
        tile[ty + j][tx] = (unsigned)f2bf(in[(size_t)(r0 + ty + j) * C + c0 + tx]);
    __syncthreads();
    for (int j = 0; j < 32; j += 8)
        out[(size_t)(c0 + ty + j) * R + r0 + tx] = (u16)tile[tx][ty + j];
}

// ---------------- layernorm over 1024, out bf16 or fp32
__global__ __launch_bounds__(256) void ln_fwd(const float* __restrict__ x, const float* __restrict__ g,
                                              const float* __restrict__ bta, void* __restrict__ outp,
                                              int out_bf16) {
    int row = blockIdx.x;
    int t = threadIdx.x;
    const float* xr = x + (size_t)row * DMODEL;
    float4 xv = *(const float4*)&xr[t * 4];
    float s = xv.x + xv.y + xv.z + xv.w;
    float s2 = xv.x * xv.x + xv.y * xv.y + xv.z * xv.z + xv.w * xv.w;
    for (int off = 32; off >= 1; off >>= 1) {
        s += __shfl_xor(s, off);
        s2 += __shfl_xor(s2, off);
    }
    __shared__ float red[10];
    int w = t >> 6;
    if ((t & 63) == 0) { red[w] = s; red[4 + w] = s2; }
    __syncthreads();
    if (t == 0) {
        red[8] = red[0] + red[1] + red[2] + red[3];
        red[9] = red[4] + red[5] + red[6] + red[7];
    }
    __syncthreads();
    float mu = red[8] * (1.0f / DMODEL);
    float var = red[9] * (1.0f / DMODEL) - mu * mu;
    float rstd = rsqrtf(var + 1e-5f);
    float vals[4] = {xv.x, xv.y, xv.z, xv.w};
    for (int e = 0; e < 4; e++) {
        int c = t * 4 + e;
        float y = (vals[e] - mu) * rstd * g[c] + bta[c];
        if (out_bf16) ((u16*)outp)[(size_t)row * DMODEL + c] = f2bf(y);
        else          ((float*)outp)[(size_t)row * DMODEL + c] = y;
    }
}

// ---------------- GEMM1: 256x256 tile, BK=64, 8 waves, 8-phase zigzag schedule
// with operand-register reuse (r12, verified: ~83 us / absmax 0.03125).
__global__ __launch_bounds__(512, 2) void gemm_8ph(const u16* __restrict__ A, const u16* __restrict__ BT,
                                                   u16* __restrict__ C, int M, int N, int K) {
    __shared__ u16 a_s[32768];   // [buf2][half2][row128][seg8][8]
    __shared__ u16 b_s[32768];
    int tid = threadIdx.x;
    int w = tid >> 6, lane = tid & 63, quad = lane >> 4, ln = lane & 15;
    int lsw = ln & 7;
    int awrow = (w >> 2) * 64 + ln;   // wave row base within A-half (+fr*16)
    int bwcol = (w & 3) * 32 + ln;    // wave col base within B-half (+fc*16)

    unsigned lin = blockIdx.x + gridDim.x * blockIdx.y;   // gridDim.x = N/256
    unsigned per = gridDim.x >> 3;
    unsigned xcd = lin & 7, tt = lin >> 3;
    unsigned n_p = xcd * per + (tt % per);
    unsigned m_p = tt / per;
    int m0 = m_p * 256, n0 = n_p * 256;

    const u16 *Ah0[2], *Ah1[2], *Bh0[2], *Bh1[2];
    int ldoff[2];
#pragma unroll
    for (int j = 0; j < 2; j++) {
        int s = j * 512 + tid;
        int row = s >> 3, seg = s & 7;
        int sw = seg ^ (row & 7);
        Ah0[j] = A + (size_t)(m0 + row) * K + sw * 8;
        Ah1[j] = A + (size_t)(m0 + 128 + row) * K + sw * 8;
        Bh0[j] = BT + (size_t)(n0 + row) * K + sw * 8;
        Bh1[j] = BT + (size_t)(n0 + 128 + row) * K + sw * 8;
        ldoff[j] = (j * 512 + w * 64) * 8;
    }

    f32x4 zero4 = {0.f, 0.f, 0.f, 0.f};
    f32x4 acc[4][4][2];   // [quadrant QM*2+QN][fr][fc]
#pragma unroll
    for (int q = 0; q < 4; q++)
#pragma unroll
        for (int fr = 0; fr < 4; fr++)
#pragma unroll
            for (int fc = 0; fc < 2; fc++) acc[q][fr][fc] = zero4;

    bf16x8 af_[4][2], bf_[2][2];   // live across phases (zigzag reuse)

#define G1_STAGE(MS, PTRS, B, H, T)                                                   \
    do {                                                                              \
        _Pragma("unroll") for (int j = 0; j < 2; j++)                                 \
            gl_lds16(PTRS[j] + (size_t)(T) * 64, &MS[((B)*2 + (H)) * 8192 + ldoff[j]]); \
    } while (0)

#define G1_PHASE(BUF, QM, QN, DOA, DOB, STAGE_STMT, TAILGATE)                         \
    do {                                                                              \
        if (DOA) {                                                                    \
            _Pragma("unroll") for (int fr = 0; fr < 4; fr++)                          \
            _Pragma("unroll") for (int ks = 0; ks < 2; ks++)                          \
                af_[fr][ks] = *(const bf16x8*)&a_s[((BUF)*2 + (QM)) * 8192 +          \
                    (awrow + fr * 16) * 64 + (((ks * 4 + quad) ^ lsw) * 8)];          \
        }                                                                             \
        if (DOB) {                                                                    \
            _Pragma("unroll") for (int fc = 0; fc < 2; fc++)                          \
            _Pragma("unroll") for (int ks = 0; ks < 2; ks++)                          \
                bf_[fc][ks] = *(const bf16x8*)&b_s[((BUF)*2 + (QN)) * 8192 +          \
                    (bwcol + fc * 16) * 64 + (((ks * 4 + quad) ^ lsw) * 8)];          \
        }                                                                             \
        STAGE_STMT;                                                                   \
        __builtin_amdgcn_s_barrier();                                                 \
        asm volatile("s_waitcnt lgkmcnt(0)" ::: "memory");                            \
        __builtin_amdgcn_sched_barrier(0);                                            \
        __builtin_amdgcn_s_setprio(1);                                                \
        _Pragma("unroll") for (int fr = 0; fr < 4; fr++)                              \
        _Pragma("unroll") for (int fc = 0; fc < 2; fc++)                              \
        _Pragma("unroll") for (int ks = 0; ks < 2; ks++)                              \
            acc[(QM)*2 + (QN)][fr][fc] = __builtin_amdgcn_mfma_f32_16x16x32_bf16(     \
                af_[fr][ks], bf_[fc][ks], acc[(QM)*2 + (QN)][fr][fc], 0, 0, 0);       \
        __builtin_amdgcn_s_setprio(0);                                                \
        TAILGATE;                                                                     \
        __builtin_amdgcn_s_barrier();                                                 \
    } while (0)

    int NT = K >> 6;   // 16

    G1_STAGE(a_s, Ah0, 0, 0, 0);
    G1_STAGE(a_s, Ah1, 0, 1, 0);
    G1_STAGE(b_s, Bh0, 0, 0, 0);
    G1_STAGE(b_s, Bh1, 0, 1, 0);
    G1_STAGE(a_s, Ah0, 1, 0, 1);
    G1_STAGE(b_s, Bh1, 1, 1, 1);
    asm volatile("s_waitcnt vmcnt(4)" ::: "memory");
    __builtin_amdgcn_s_barrier();

    for (int t = 0; t < NT; t++) {
        int buf = t & 1, nb = buf ^ 1;
        G1_PHASE(buf, 0, 0, 1, 1, { if (t + 1 < NT) G1_STAGE(a_s, Ah1, nb, 1, t + 1); }, {});
        G1_PHASE(buf, 0, 1, 0, 1, { if (t + 1 < NT) G1_STAGE(b_s, Bh0, nb, 0, t + 1); }, {});
        G1_PHASE(buf, 1, 1, 1, 0, { if (t + 2 < NT) G1_STAGE(a_s, Ah0, buf, 0, t + 2); }, {});
        G1_PHASE(buf, 1, 0, 0, 1, { if (t + 2 < NT) G1_STAGE(b_s, Bh1, buf, 1, t + 2); },
                 {
                     if (t + 2 < NT) asm volatile("s_waitcnt vmcnt(4)" ::: "memory");
                     else            asm volatile("s_waitcnt vmcnt(0)" ::: "memory");
                 });
    }

#undef G1_STAGE
#undef G1_PHASE

#pragma unroll
    for (int QM = 0; QM < 2; QM++)
#pragma unroll
        for (int QN = 0; QN < 2; QN++)
#pragma unroll
            for (int fr = 0; fr < 4; fr++)
#pragma unroll
                for (int fc = 0; fc < 2; fc++)
#pragma unroll
                    for (int e = 0; e < 4; e++) {
                        int row = m0 + QM * 128 + (w >> 2) * 64 + fr * 16 + quad * 4 + e;
                        int col = n0 + QN * 128 + (w & 3) * 32 + fc * 16 + ln;
                        C[(size_t)row * N + col] = f2bf(acc[QM * 2 + QN][fr][fc][e]);
                    }
}

// ---------------- GEMM2: 64x128 tile, BK=64 (r13, verified). 512 blocks =
// 2 blocks/CU; LDS 48KB dbuf; 3-bit seg-XOR swizzle.
__global__ __launch_bounds__(256) void gemm_bt64(const u16* __restrict__ A, const u16* __restrict__ BT,
                                                 float* __restrict__ C, int M, int N, int K) {
    __shared__ u16 a_s[2][4096];   // dbuf x [row64][seg8][8]
    __shared__ u16 b_s[2][8192];   // dbuf x [row128][seg8][8]
    int tid = threadIdx.x;
    unsigned NX = gridDim.x;       // N/128 = 8
    unsigned lin = blockIdx.x + NX * blockIdx.y;
    unsigned per = NX >> 3;
    unsigned xcd = lin & 7, t = lin >> 3;
    unsigned n_p = xcd * per + (t % per);
    unsigned m_p = t / per;
    int m0 = m_p * 64, n0 = n_p * 128;
    int w = tid >> 6, lane = tid & 63, quad = lane >> 4, ln = lane & 15;
    int wc = w * 32, lsw = ln & 7;
    f32x4 zero4 = {0.f, 0.f, 0.f, 0.f};
    f32x4 acc[4][2];
    for (int r = 0; r < 4; r++)
        for (int c = 0; c < 2; c++) acc[r][c] = zero4;

    const u16* Ag[2];
    int aoff[2];
#pragma unroll
    for (int j = 0; j < 2; j++) {
        int s = j * 256 + tid;
        int row = s >> 3, seg = s & 7;
        Ag[j] = A + (size_t)(m0 + row) * K + (seg ^ (row & 7)) * 8;
        aoff[j] = s * 8;
    }
    const u16* Bg[4];
    int boff[4];
#pragma unroll
    for (int j = 0; j < 4; j++) {
        int s = j * 256 + tid;
        int row = s >> 3, seg = s & 7;
        Bg[j] = BT + (size_t)(n0 + row) * K + (seg ^ (row & 7)) * 8;
        boff[j] = s * 8;
    }

    for (int j = 0; j < 2; j++) gl_lds16(Ag[j], &a_s[0][aoff[j]]);
    for (int j = 0; j < 4; j++) gl_lds16(Bg[j], &b_s[0][boff[j]]);
    __syncthreads();

    int cur = 0;
    for (int k0 = 0; k0 < K; k0 += 64) {
        if (k0 + 64 < K) {
            int nb = cur ^ 1;
            for (int j = 0; j < 2; j++) gl_lds16(Ag[j] + k0 + 64, &a_s[nb][aoff[j]]);
            for (int j = 0; j < 4; j++) gl_lds16(Bg[j] + k0 + 64, &b_s[nb][boff[j]]);
        }
        bf16x8 af[4][2], bfr[2][2];
#pragma unroll
        for (int r = 0; r < 4; r++)
#pragma unroll
            for (int ks = 0; ks < 2; ks++)
                af[r][ks] = *(const bf16x8*)&a_s[cur][(r * 16 + ln) * 64 + (((ks * 4 + quad) ^ lsw) * 8)];
#pragma unroll
        for (int c = 0; c < 2; c++)
#pragma unroll
            for (int ks = 0; ks < 2; ks++)
                bfr[c][ks] = *(const bf16x8*)&b_s[cur][(wc + c * 16 + ln) * 64 + (((ks * 4 + quad) ^ lsw) * 8)];
        __builtin_amdgcn_s_setprio(1);
#pragma unroll
        for (int r = 0; r < 4; r++)
#pragma unroll
            for (int c = 0; c < 2; c++)
#pragma unroll
                for (int ks = 0; ks < 2; ks++)
                    acc[r][c] = __builtin_amdgcn_mfma_f32_16x16x32_bf16(af[r][ks], bfr[c][ks], acc[r][c], 0, 0, 0);
        __builtin_amdgcn_s_setprio(0);
        __syncthreads();
        cur ^= 1;
    }
    for (int r = 0; r < 4; r++)
        for (int c = 0; c < 2; c++)
            for (int e = 0; e < 4; e++) {
                int row = m0 + r * 16 + quad * 4 + e;
                int col = n0 + wc + c * 16 + ln;
                C[(size_t)row * N + col] = acc[r][c][e];
            }
}

// ---------------- fused per-(b,h) V-transpose + K-smear (r13, verified)
__global__ void vT_smear(const u16* __restrict__ qkvp, const float* __restrict__ smear_f,
                         u16* __restrict__ v_t, u16* __restrict__ k_sm) {
    __shared__ unsigned tile[32][33];
    int bh = blockIdx.z;
    int bb = bh >> 4, h = bh & 15;
    int tx = threadIdx.x, ty = threadIdx.y;
    size_t tokb = (size_t)bb * L_SEQ;
    if (blockIdx.y < 4) {
        int l0 = blockIdx.x * 32, d0 = blockIdx.y * 32;
        for (int j = 0; j < 32; j += 8)
            tile[ty + j][tx] = (unsigned)qkvp[(tokb + l0 + ty + j) * 8192 + 4096 + h * DH + d0 + tx];
        __syncthreads();
        for (int j = 0; j < 32; j += 8)
            v_t[((size_t)bh * DH + d0 + ty + j) * L_SEQ + l0 + tx] = (u16)tile[tx][ty + j];
    } else {
        int l0 = blockIdx.x * 32;
        int tid = ty * 32 + tx;
        float s = 1.0f / (1.0f + __expf(-smear_f[h]));
        for (int p = 0; p < 2; p++) {
            int v = tid + p * 256;       // 0..511
            int lr = v >> 4;             // 0..31
            int d = (v & 15) * 8;
            int l = l0 + lr;
            u16x8 cur = *(const u16x8*)&qkvp[(tokb + l) * 8192 + 2048 + h * DH + d];
            u16x8 prv = {0, 0, 0, 0, 0, 0, 0, 0};
            if (l > 0) prv = *(const u16x8*)&qkvp[(tokb + l - 1) * 8192 + 2048 + h * DH + d];
            u16x8 outv;
            for (int u = 0; u < 8; u++) {
                float kc = bf2f(cur[u]);
                float kp = bf2f(prv[u]);
                outv[u] = f2bf((1.0f - s) * kc + s * kp);
            }
            *(u16x8*)&k_sm[(((size_t)bh) * L_SEQ + l) * DH + d] = outv;
        }
    }
}

// ---------------- flash attention + SiLU(p) gating (round-12/13 version,
// REVERTED from r14's 4-context split which measured 94.6 -> 107 us:
// serial + swapped-operand QK^T + adt-shift + v_perm pack + max3 tree,
// K/V dbuf stage-ahead, XCD head-clustering. ~93-94.6 us measured.)
__global__ __launch_bounds__(256) void attn_kernel(const u16* __restrict__ qkvp,
                                                   const u16* __restrict__ k_sm,
                                                   const u16* __restrict__ v_t,
                                                   u16* __restrict__ ag2,
                                                   const float* __restrict__ log_scale) {
    __shared__ u16 k_s[16384];   // 2 bufs x [kt 0..3][jrow 0..63][32 k] (swizzled content)
    __shared__ u16 vt_s[16384];  // 2 bufs x [jt 0..1][d 0..127][32 j]  (swizzled content)
    __shared__ u16 p_s[4608];    // per-wave 16 x 72 (single buffer)
    int tid = threadIdx.x;
    // XCD clustering: lin%8 = XCD (round-robin dispatch); 4 heads per XCD.
    unsigned lin = blockIdx.x + 16u * blockIdx.y;
    unsigned xcd = lin & 7, tt = lin >> 3;
    int bh = (int)(xcd * 4 + (tt & 3));
    int pair = (int)(tt >> 2);
    int bb = bh >> 4, h = bh & 15;
    int w = tid >> 6, lane = tid & 63, quad = lane >> 4, ln = lane & 15;
    size_t tokb = (size_t)bb * L_SEQ;

    const float LOG2E = 1.44269504f;
    float inv = 1.0f / (__expf(2.0f * log_scale[h]) * sqrtf((float)DH));
    float scl = inv * LOG2E;
    float slope2 = ((h < 8) ? exp2f(-8.0f * (float)h / 7.0f) : 0.0f) * LOG2E;

    int lrow = lane >> 2, lcol = lane & 3;
    int lsw8 = (lcol ^ ((lrow >> 1) & 3)) * 8;  // write-side swizzle via global source addr
    int qsw = (quad ^ ((ln >> 1) & 3)) * 8;     // read-side swizzle (same involution)
    f32x4 zero4 = {0.f, 0.f, 0.f, 0.f};
    u16* pw = &p_s[w * 1152];
    const short ONE_BF = (short)0x3F80;
    bf16x8 ones = {ONE_BF, ONE_BF, ONE_BF, ONE_BF, ONE_BF, ONE_BF, ONE_BF, ONE_BF};

    for (int sidx = 0; sidx < 2; sidx++) {
        int ib = sidx == 0 ? (31 - pair) : pair;
        int i0 = ib * 64;
        int si = i0 + w * 16;
        int iq = si + ln;          // this lane's q-row (swapped layout)

        // Q fragments straight from global (same data serves as B-operand now)
        bf16x8 qf[4];
        for (int kt = 0; kt < 4; kt++)
            qf[kt] = *(const bf16x8*)&qkvp[(tokb + si + ln) * 8192 + h * DH + kt * 32 + quad * 8];

        // shifted-domain running max: m_true(t) = mshift(t) + slope2*j0(t)
        float mshift = -1e30f;
        float astep = slope2 * 64.0f;
        f32x4 o_acc[8], l_acc;
        for (int dt = 0; dt < 8; dt++) o_acc[dt] = zero4;
        l_acc = zero4;

        // FIXED ALiBi base table (no per-iter increment)
        float adt0[4][4];
        for (int ct = 0; ct < 4; ct++)
            for (int r = 0; r < 4; r++)
                adt0[ct][r] = slope2 * (float)(ct * 16 + quad * 4 + r);

        // staging pointers: advance by constant per j-tile (pre-swizzled source)
        const u16* kg[4];
        for (int g = 0; g < 4; g++)
            kg[g] = k_sm + ((size_t)bh * L_SEQ + g * 16 + lrow) * DH + w * 32 + lsw8;
        const u16* vg[4];
        int vloff[4];
        for (int q = 0; q < 4; q++) {
            int c = w * 4 + q;
            int jt = c >> 3, dg = c & 7;
            vg[q] = v_t + ((size_t)bh * DH + dg * 16 + lrow) * L_SEQ + jt * 32 + lsw8;
            vloff[q] = jt * 4096 + dg * 512;
        }

        // prologue: stage j-tile 0 into buffer 0
        for (int g = 0; g < 4; g++) { gl_lds16(kg[g], &k_s[w * 2048 + g * 512]); kg[g] += 64 * DH; }
        for (int q = 0; q < 4; q++) { gl_lds16(vg[q], &vt_s[vloff[q]]); vg[q] += 64; }
        __syncthreads();

        int cur = 0;
        for (int j0 = 0; j0 <= i0; j0 += 64) {
            // stage NEXT tile into the other buffer; in flight across compute
            if (j0 + 64 <= i0) {
                int nb = (cur ^ 1) * 8192;
                for (int g = 0; g < 4; g++) { gl_lds16(kg[g], &k_s[nb + w * 2048 + g * 512]); kg[g] += 64 * DH; }
                for (int q = 0; q < 4; q++) { gl_lds16(vg[q], &vt_s[nb + vloff[q]]); vg[q] += 64; }
            }
            const u16* kb = &k_s[cur * 8192];
            const u16* vb = &vt_s[cur * 8192];

            // S^T = K Q^T: swapped operands. Lane: sc[ct][r] = S[si+ln][j0 + ct*16 + quad*4 + r]
            f32x4 sc[4];
            for (int ct = 0; ct < 4; ct++) sc[ct] = zero4;
            __builtin_amdgcn_s_setprio(1);
            for (int kt = 0; kt < 4; kt++)
                for (int ct = 0; ct < 4; ct++) {
                    bf16x8 bfr = *(const bf16x8*)&kb[kt * 2048 + (ct * 16 + ln) * 32 + qsw];
                    sc[ct] = __builtin_amdgcn_mfma_f32_16x16x32_bf16(bfr, qf[kt], sc[ct], 0, 0, 0);
                }
            __builtin_amdgcn_s_setprio(0);

            // shifted scores: s_true = s2 + slope2*j0 (uniform) -- never materialized
            bool full = (j0 + 63 <= si);
            float s2[4][4];
            for (int ct = 0; ct < 4; ct++)
                for (int r = 0; r < 4; r++) {
                    float v = fmaf(sc[ct][r], scl, adt0[ct][r]);
                    if (!full) {
                        int j = j0 + ct * 16 + quad * 4 + r;
                        if (j > iq) v = -3.0e38f;
                    }
                    s2[ct][r] = v;
                }
            // row max in shifted domain: max3-shaped tree + cross-quad reduce
            float x0 = fmaxf(fmaxf(s2[0][0], s2[0][1]), s2[0][2]);
            float x1 = fmaxf(fmaxf(s2[0][3], s2[1][0]), s2[1][1]);
            float x2 = fmaxf(fmaxf(s2[1][2], s2[1][3]), s2[2][0]);
            float x3 = fmaxf(fmaxf(s2[2][1], s2[2][2]), s2[2][3]);
            float x4 = fmaxf(fmaxf(s2[3][0], s2[3][1]), s2[3][2]);
            float y0 = fmaxf(fmaxf(x0, x1), x2);
            float y1 = fmaxf(fmaxf(x3, x4), s2[3][3]);
            float mr = fmaxf(y0, y1);
            mr = fmaxf(mr, __shfl_xor(mr, 16));
            mr = fmaxf(mr, __shfl_xor(mr, 32));
            // shifted-domain update: m_old_shift(this iter) = mshift - astep
            float msh_old = mshift - astep;
            float mnew = fmaxf(msh_old, mr);
            float alpha = exp2f(msh_old - mnew);
            mshift = mnew;

            // P: exp2 in shifted domain, v_perm pack, 4x ds_write_b64
            for (int ct = 0; ct < 4; ct++) {
                float p0 = exp2f(s2[ct][0] - mnew);
                float p1 = exp2f(s2[ct][1] - mnew);
                float p2 = exp2f(s2[ct][2] - mnew);
                float p3 = exp2f(s2[ct][3] - mnew);
                unsigned d0 = __builtin_amdgcn_perm(__float_as_uint(p1), __float_as_uint(p0), 0x07060302u);
                unsigned d1 = __builtin_amdgcn_perm(__float_as_uint(p3), __float_as_uint(p2), 0x07060302u);
                uint2 dd; dd.x = d0; dd.y = d1;
                *(uint2*)&pw[ln * 72 + ct * 16 + quad * 4] = dd;
            }

            // rescale O/l: gather alpha for rows quad*4+e from lanes (quad*16)+(quad*4+e)
            if (__any(alpha != 1.0f)) {
                float av[4];
                for (int e = 0; e < 4; e++) av[e] = __shfl(alpha, quad * 20 + e);
                for (int dt = 0; dt < 8; dt++) {
                    f32x4 o = o_acc[dt];
                    for (int e = 0; e < 4; e++) o[e] *= av[e];
                    o_acc[dt] = o;
                }
                for (int e = 0; e < 4; e++) l_acc[e] *= av[e];
            }
            asm volatile("s_waitcnt lgkmcnt(0)" ::: "memory");
            __builtin_amdgcn_s_setprio(1);
            for (int ks = 0; ks < 2; ks++) {
                bf16x8 pa = *(const bf16x8*)&pw[ln * 72 + ks * 32 + quad * 8];
                l_acc = __builtin_amdgcn_mfma_f32_16x16x32_bf16(pa, ones, l_acc, 0, 0, 0);
                for (int dt = 0; dt < 8; dt++) {
                    bf16x8 vf = *(const bf16x8*)&vb[ks * 4096 + (dt * 16 + ln) * 32 + qsw];
                    o_acc[dt] = __builtin_amdgcn_mfma_f32_16x16x32_bf16(pa, vf, o_acc[dt], 0, 0, 0);
                }
            }
            __builtin_amdgcn_s_setprio(0);
            __syncthreads();
            cur ^= 1;
        }

        // epilogue: normalize (rcp), SiLU(p) gate (exp2+rcp), store bf16
        float rinv[4];
        for (int r = 0; r < 4; r++) rinv[r] = __builtin_amdgcn_rcpf(l_acc[r]);
        for (int dt = 0; dt < 8; dt++)
            for (int r = 0; r < 4; r++) {
                int i = si + quad * 4 + r;
                int dcol = dt * 16 + ln;
                float o = o_acc[dt][r] * rinv[r];
                float pv = bf2f(qkvp[(tokb + i) * 8192 + 6144 + h * DH + dcol]);
                float gate = pv * __builtin_amdgcn_rcpf(1.0f + exp2f(-pv * LOG2E));
                ag2[(tokb + i) * 2048 + h * DH + dcol] = f2bf(gate * o);
            }
    }
}

extern "C" void kernel_launch(void* const* d_in, const int* in_sizes, int n_in,
                              void* d_out, int out_size, void* d_ws, size_t ws_size,
                              hipStream_t stream) {
    const float* x       = (const float*)d_in[0];
    const float* ln1_g   = (const float*)d_in[1];
    const float* ln1_b   = (const float*)d_in[2];
    const float* ln2_g   = (const float*)d_in[3];
    const float* ln2_b   = (const float*)d_in[4];
    const float* w_in    = (const float*)d_in[5];
    const float* w_out   = (const float*)d_in[6];
    const float* smear_f = (const float*)d_in[7];
    const float* logsc   = (const float*)d_in[8];
    float* out = (float*)d_out;
    char* ws = (char*)d_ws;

    // ws layout (bytes)
    u16* w_inT   = (u16*)(ws + 0);                       // 16 MB  [8192,1024]
    u16* w_outT  = (u16*)(ws + (size_t)16777216);        //  4 MB  [1024,2048]
    u16* lnA     = (u16*)(ws + (size_t)20971520);        //  8 MB  [4096,1024]
    u16* qkvp    = (u16*)(ws + (size_t)29360128);        // 64 MB  [4096,8192]
    u16* k_sm    = (u16*)(ws + (size_t)96468992);        // 16 MB  [bh][l][128]
    u16* ag2     = (u16*)(ws + (size_t)113246208);       // 16 MB  [4096,2048]
    float* out_pre = (float*)(ws + (size_t)96468992);    // alias k_sm (dead after attn)
    u16* v_t     = (u16*)(ws + 0);                       // alias w_inT (dead after gemm1)

    dim3 b32x8(32, 8);
    conv_transpose<<<dim3(8192 / 32, 1024 / 32), b32x8, 0, stream>>>(w_in, w_inT, 1024, 8192);
    conv_transpose<<<dim3(1024 / 32, 2048 / 32), b32x8, 0, stream>>>(w_out, w_outT, 2048, 1024);
    ln_fwd<<<NTOK, 256, 0, stream>>>(x, ln1_g, ln1_b, (void*)lnA, 1);
    gemm_8ph<<<dim3(8192 / 256, 4096 / 256), 512, 0, stream>>>(lnA, w_inT, qkvp, NTOK, 8192, 1024);
    vT_smear<<<dim3(L_SEQ / 32, 5, 32), b32x8, 0, stream>>>(qkvp, smear_f, v_t, k_sm);
    attn_kernel<<<dim3(16, 32), 256, 0, stream>>>(qkvp, k_sm, v_t, ag2, logsc);
    gemm_bt64<<<dim3(1024 / 128, 4096 / 64), 256, 0, stream>>>(ag2, w_outT, out_pre, NTOK, 1024, 2048);
    ln_fwd<<<NTOK, 256, 0, stream>>>(out_pre, ln2_g, ln2_b, (void*)out, 0);
}

// Round 16
// 322.922 us; speedup vs baseline: 1.0353x; 1.0035x over previous
//
#include <hip/hip_runtime.h>

typedef unsigned short u16;
typedef __attribute__((ext_vector_type(8))) short bf16x8;
typedef __attribute__((ext_vector_type(8))) unsigned short u16x8;
typedef __attribute__((ext_vector_type(4))) float f32x4;

#define L_SEQ 2048
#define NTOK 4096   // B*L
#define DMODEL 1024
#define DEXP 2048
#define NH 16
#define DH 128

__device__ __forceinline__ u16 f2bf(float f) {
    unsigned u = __float_as_uint(f);
    unsigned r = (u + 0x7FFFu + ((u >> 16) & 1u)) >> 16;
    return (u16)r;
}
__device__ __forceinline__ float bf2f(u16 h) {
    return __uint_as_float(((unsigned)h) << 16);
}

// async global->LDS, 16B per lane; LDS dest = wave-uniform base + lane*16
__device__ __forceinline__ void gl_lds16(const u16* g, u16* l) {
    __builtin_amdgcn_global_load_lds((const __attribute__((address_space(1))) void*)g,
                                     (__attribute__((address_space(3))) void*)l, 16, 0, 0);
}

// ---------------- convert + transpose fp32 -> bf16, out[c*R + r] = in[r*C + c]
// Round-16: 64(r) x 32(c) tile, u32 stores (2 r-values per thread; out is
// contiguous in r). Was 2B/lane scalar stores = half-width coalescing (G13).
// tile padded [64][34]: both LDS phases 2-way bank aliasing (free, m136).
__global__ void conv_transpose(const float* __restrict__ in, u16* __restrict__ out, int R, int C) {
    __shared__ u16 tile[64][34];
    int c0 = blockIdx.x * 32, r0 = blockIdx.y * 64;
    int tx = threadIdx.x, ty = threadIdx.y;   // block (32,8)
    for (int j = 0; j < 64; j += 8)
        tile[ty + j][tx] = f2bf(in[(size_t)(r0 + ty + j) * C + c0 + tx]);
    __syncthreads();
    for (int j = 0; j < 32; j += 8) {
        int cl = ty + j;
        unsigned v = (unsigned)tile[2 * tx][cl] | ((unsigned)tile[2 * tx + 1][cl] << 16);
        *(unsigned*)&out[(size_t)(c0 + cl) * R + r0 + 2 * tx] = v;
    }
}

// ---------------- layernorm over 1024, out bf16 or fp32
__global__ __launch_bounds__(256) void ln_fwd(const float* __restrict__ x, const float* __restrict__ g,
                                              const float* __restrict__ bta, void* __restrict__ outp,
                                              int out_bf16) {
    int row = blockIdx.x;
    int t = threadIdx.x;
    const float* xr = x + (size_t)row * DMODEL;
    float4 xv = *(const float4*)&xr[t * 4];
    float s = xv.x + xv.y + xv.z + xv.w;
    float s2 = xv.x * xv.x + xv.y * xv.y + xv.z * xv.z + xv.w * xv.w;
    for (int off = 32; off >= 1; off >>= 1) {
        s += __shfl_xor(s, off);
        s2 += __shfl_xor(s2, off);
    }
    __shared__ float red[10];
    int w = t >> 6;
    if ((t & 63) == 0) { red[w] = s; red[4 + w] = s2; }
    __syncthreads();
    if (t == 0) {
        red[8] = red[0] + red[1] + red[2] + red[3];
        red[9] = red[4] + red[5] + red[6] + red[7];
    }
    __syncthreads();
    float mu = red[8] * (1.0f / DMODEL);
    float var = red[9] * (1.0f / DMODEL) - mu * mu;
    float rstd = rsqrtf(var + 1e-5f);
    float vals[4] = {xv.x, xv.y, xv.z, xv.w};
    for (int e = 0; e < 4; e++) {
        int c = t * 4 + e;
        float y = (vals[e] - mu) * rstd * g[c] + bta[c];
        if (out_bf16) ((u16*)outp)[(size_t)row * DMODEL + c] = f2bf(y);
        else          ((float*)outp)[(size_t)row * DMODEL + c] = y;
    }
}

// ---------------- GEMM1: 256x256 tile, BK=64, 8 waves, 8-phase zigzag schedule
// with operand-register reuse (r12, verified: ~83 us / absmax 0.03125).
__global__ __launch_bounds__(512, 2) void gemm_8ph(const u16* __restrict__ A, const u16* __restrict__ BT,
                                                   u16* __restrict__ C, int M, int N, int K) {
    __shared__ u16 a_s[32768];   // [buf2][half2][row128][seg8][8]
    __shared__ u16 b_s[32768];
    int tid = threadIdx.x;
    int w = tid >> 6, lane = tid & 63, quad = lane >> 4, ln = lane & 15;
    int lsw = ln & 7;
    int awrow = (w >> 2) * 64 + ln;   // wave row base within A-half (+fr*16)
    int bwcol = (w & 3) * 32 + ln;    // wave col base within B-half (+fc*16)

    unsigned lin = blockIdx.x + gridDim.x * blockIdx.y;   // gridDim.x = N/256
    unsigned per = gridDim.x >> 3;
    unsigned xcd = lin & 7, tt = lin >> 3;
    unsigned n_p = xcd * per + (tt % per);
    unsigned m_p = tt / per;
    int m0 = m_p * 256, n0 = n_p * 256;

    const u16 *Ah0[2], *Ah1[2], *Bh0[2], *Bh1[2];
    int ldoff[2];
#pragma unroll
    for (int j = 0; j < 2; j++) {
        int s = j * 512 + tid;
        int row = s >> 3, seg = s & 7;
        int sw = seg ^ (row & 7);
        Ah0[j] = A + (size_t)(m0 + row) * K + sw * 8;
        Ah1[j] = A + (size_t)(m0 + 128 + row) * K + sw * 8;
        Bh0[j] = BT + (size_t)(n0 + row) * K + sw * 8;
        Bh1[j] = BT + (size_t)(n0 + 128 + row) * K + sw * 8;
        ldoff[j] = (j * 512 + w * 64) * 8;
    }

    f32x4 zero4 = {0.f, 0.f, 0.f, 0.f};
    f32x4 acc[4][4][2];   // [quadrant QM*2+QN][fr][fc]
#pragma unroll
    for (int q = 0; q < 4; q++)
#pragma unroll
        for (int fr = 0; fr < 4; fr++)
#pragma unroll
            for (int fc = 0; fc < 2; fc++) acc[q][fr][fc] = zero4;

    bf16x8 af_[4][2], bf_[2][2];   // live across phases (zigzag reuse)

#define G1_STAGE(MS, PTRS, B, H, T)                                                   \
    do {                                                                              \
        _Pragma("unroll") for (int j = 0; j < 2; j++)                                 \
            gl_lds16(PTRS[j] + (size_t)(T) * 64, &MS[((B)*2 + (H)) * 8192 + ldoff[j]]); \
    } while (0)

#define G1_PHASE(BUF, QM, QN, DOA, DOB, STAGE_STMT, TAILGATE)                         \
    do {                                                                              \
        if (DOA) {                                                                    \
            _Pragma("unroll") for (int fr = 0; fr < 4; fr++)                          \
            _Pragma("unroll") for (int ks = 0; ks < 2; ks++)                          \
                af_[fr][ks] = *(const bf16x8*)&a_s[((BUF)*2 + (QM)) * 8192 +          \
                    (awrow + fr * 16) * 64 + (((ks * 4 + quad) ^ lsw) * 8)];          \
        }                                                                             \
        if (DOB) {                                                                    \
            _Pragma("unroll") for (int fc = 0; fc < 2; fc++)                          \
            _Pragma("unroll") for (int ks = 0; ks < 2; ks++)                          \
                bf_[fc][ks] = *(const bf16x8*)&b_s[((BUF)*2 + (QN)) * 8192 +          \
                    (bwcol + fc * 16) * 64 + (((ks * 4 + quad) ^ lsw) * 8)];          \
        }                                                                             \
        STAGE_STMT;                                                                   \
        __builtin_amdgcn_s_barrier();                                                 \
        asm volatile("s_waitcnt lgkmcnt(0)" ::: "memory");                            \
        __builtin_amdgcn_sched_barrier(0);                                            \
        __builtin_amdgcn_s_setprio(1);                                                \
        _Pragma("unroll") for (int fr = 0; fr < 4; fr++)                              \
        _Pragma("unroll") for (int fc = 0; fc < 2; fc++)                              \
        _Pragma("unroll") for (int ks = 0; ks < 2; ks++)                              \
            acc[(QM)*2 + (QN)][fr][fc] = __builtin_amdgcn_mfma_f32_16x16x32_bf16(     \
                af_[fr][ks], bf_[fc][ks], acc[(QM)*2 + (QN)][fr][fc], 0, 0, 0);       \
        __builtin_amdgcn_s_setprio(0);                                                \
        TAILGATE;                                                                     \
        __builtin_amdgcn_s_barrier();                                                 \
    } while (0)

    int NT = K >> 6;   // 16

    G1_STAGE(a_s, Ah0, 0, 0, 0);
    G1_STAGE(a_s, Ah1, 0, 1, 0);
    G1_STAGE(b_s, Bh0, 0, 0, 0);
    G1_STAGE(b_s, Bh1, 0, 1, 0);
    G1_STAGE(a_s, Ah0, 1, 0, 1);
    G1_STAGE(b_s, Bh1, 1, 1, 1);
    asm volatile("s_waitcnt vmcnt(4)" ::: "memory");
    __builtin_amdgcn_s_barrier();

    for (int t = 0; t < NT; t++) {
        int buf = t & 1, nb = buf ^ 1;
        G1_PHASE(buf, 0, 0, 1, 1, { if (t + 1 < NT) G1_STAGE(a_s, Ah1, nb, 1, t + 1); }, {});
        G1_PHASE(buf, 0, 1, 0, 1, { if (t + 1 < NT) G1_STAGE(b_s, Bh0, nb, 0, t + 1); }, {});
        G1_PHASE(buf, 1, 1, 1, 0, { if (t + 2 < NT) G1_STAGE(a_s, Ah0, buf, 0, t + 2); }, {});
        G1_PHASE(buf, 1, 0, 0, 1, { if (t + 2 < NT) G1_STAGE(b_s, Bh1, buf, 1, t + 2); },
                 {
                     if (t + 2 < NT) asm volatile("s_waitcnt vmcnt(4)" ::: "memory");
                     else            asm volatile("s_waitcnt vmcnt(0)" ::: "memory");
                 });
    }

#undef G1_STAGE
#undef G1_PHASE

#pragma unroll
    for (int QM = 0; QM < 2; QM++)
#pragma unroll
        for (int QN = 0; QN < 2; QN++)
#pragma unroll
            for (int fr = 0; fr < 4; fr++)
#pragma unroll
                for (int fc = 0; fc < 2; fc++)
#pragma unroll
                    for (int e = 0; e < 4; e++) {
                        int row = m0 + QM * 128 + (w >> 2) * 64 + fr * 16 + quad * 4 + e;
                        int col = n0 + QN * 128 + (w & 3) * 32 + fc * 16 + ln;
                        C[(size_t)row * N + col] = f2bf(acc[QM * 2 + QN][fr][fc][e]);
                    }
}

// ---------------- GEMM2: 64x128 tile, BK=64 (r13, verified). 512 blocks =
// 2 blocks/CU; LDS 48KB dbuf; 3-bit seg-XOR swizzle.
__global__ __launch_bounds__(256) void gemm_bt64(const u16* __restrict__ A, const u16* __restrict__ BT,
                                                 float* __restrict__ C, int M, int N, int K) {
    __shared__ u16 a_s[2][4096];   // dbuf x [row64][seg8][8]
    __shared__ u16 b_s[2][8192];   // dbuf x [row128][seg8][8]
    int tid = threadIdx.x;
    unsigned NX = gridDim.x;       // N/128 = 8
    unsigned lin = blockIdx.x + NX * blockIdx.y;
    unsigned per = NX >> 3;
    unsigned xcd = lin & 7, t = lin >> 3;
    unsigned n_p = xcd * per + (t % per);
    unsigned m_p = t / per;
    int m0 = m_p * 64, n0 = n_p * 128;
    int w = tid >> 6, lane = tid & 63, quad = lane >> 4, ln = lane & 15;
    int wc = w * 32, lsw = ln & 7;
    f32x4 zero4 = {0.f, 0.f, 0.f, 0.f};
    f32x4 acc[4][2];
    for (int r = 0; r < 4; r++)
        for (int c = 0; c < 2; c++) acc[r][c] = zero4;

    const u16* Ag[2];
    int aoff[2];
#pragma unroll
    for (int j = 0; j < 2; j++) {
        int s = j * 256 + tid;
        int row = s >> 3, seg = s & 7;
        Ag[j] = A + (size_t)(m0 + row) * K + (seg ^ (row & 7)) * 8;
        aoff[j] = s * 8;
    }
    const u16* Bg[4];
    int boff[4];
#pragma unroll
    for (int j = 0; j < 4; j++) {
        int s = j * 256 + tid;
        int row = s >> 3, seg = s & 7;
        Bg[j] = BT + (size_t)(n0 + row) * K + (seg ^ (row & 7)) * 8;
        boff[j] = s * 8;
    }

    for (int j = 0; j < 2; j++) gl_lds16(Ag[j], &a_s[0][aoff[j]]);
    for (int j = 0; j < 4; j++) gl_lds16(Bg[j], &b_s[0][boff[j]]);
    __syncthreads();

    int cur = 0;
    for (int k0 = 0; k0 < K; k0 += 64) {
        if (k0 + 64 < K) {
            int nb = cur ^ 1;
            for (int j = 0; j < 2; j++) gl_lds16(Ag[j] + k0 + 64, &a_s[nb][aoff[j]]);
            for (int j = 0; j < 4; j++) gl_lds16(Bg[j] + k0 + 64, &b_s[nb][boff[j]]);
        }
        bf16x8 af[4][2], bfr[2][2];
#pragma unroll
        for (int r = 0; r < 4; r++)
#pragma unroll
            for (int ks = 0; ks < 2; ks++)
                af[r][ks] = *(const bf16x8*)&a_s[cur][(r * 16 + ln) * 64 + (((ks * 4 + quad) ^ lsw) * 8)];
#pragma unroll
        for (int c = 0; c < 2; c++)
#pragma unroll
            for (int ks = 0; ks < 2; ks++)
                bfr[c][ks] = *(const bf16x8*)&b_s[cur][(wc + c * 16 + ln) * 64 + (((ks * 4 + quad) ^ lsw) * 8)];
        __builtin_amdgcn_s_setprio(1);
#pragma unroll
        for (int r = 0; r < 4; r++)
#pragma unroll
            for (int c = 0; c < 2; c++)
#pragma unroll
                for (int ks = 0; ks < 2; ks++)
                    acc[r][c] = __builtin_amdgcn_mfma_f32_16x16x32_bf16(af[r][ks], bfr[c][ks], acc[r][c], 0, 0, 0);
        __builtin_amdgcn_s_setprio(0);
        __syncthreads();
        cur ^= 1;
    }
    for (int r = 0; r < 4; r++)
        for (int c = 0; c < 2; c++)
            for (int e = 0; e < 4; e++) {
                int row = m0 + r * 16 + quad * 4 + e;
                int col = n0 + wc + c * 16 + ln;
                C[(size_t)row * N + col] = acc[r][c][e];
            }
}

// ---------------- fused per-(b,h) V-transpose + K-smear
// Round-16: vT plane uses 64(l) x 32(d) tiles with u32 stores (2 l-values per
// thread; v_t is contiguous in l). Was 2B/lane scalar stores. Smear plane
// covers 64 l per block (grid x halved), otherwise identical.
__global__ void vT_smear(const u16* __restrict__ qkvp, const float* __restrict__ smear_f,
                         u16* __restrict__ v_t, u16* __restrict__ k_sm) {
    __shared__ u16 tile[64][34];
    int bh = blockIdx.z;
    int bb = bh >> 4, h = bh & 15;
    int tx = threadIdx.x, ty = threadIdx.y;   // block (32,8)
    size_t tokb = (size_t)bb * L_SEQ;
    if (blockIdx.y < 4) {
        int l0 = blockIdx.x * 64, d0 = blockIdx.y * 32;
        for (int j = 0; j < 64; j += 8)
            tile[ty + j][tx] = qkvp[(tokb + l0 + ty + j) * 8192 + 4096 + h * DH + d0 + tx];
        __syncthreads();
        for (int j = 0; j < 32; j += 8) {
            int dl = ty + j;
            unsigned v = (unsigned)tile[2 * tx][dl] | ((unsigned)tile[2 * tx + 1][dl] << 16);
            *(unsigned*)&v_t[((size_t)bh * DH + d0 + dl) * L_SEQ + l0 + 2 * tx] = v;
        }
    } else {
        int l0 = blockIdx.x * 64;
        int tid = ty * 32 + tx;
        float s = 1.0f / (1.0f + __expf(-smear_f[h]));
        for (int p = 0; p < 4; p++) {
            int v = tid + p * 256;       // 0..1023: 64 l x 16 d-segments
            int lr = v >> 4;             // 0..63
            int d = (v & 15) * 8;
            int l = l0 + lr;
            u16x8 cur = *(const u16x8*)&qkvp[(tokb + l) * 8192 + 2048 + h * DH + d];
            u16x8 prv = {0, 0, 0, 0, 0, 0, 0, 0};
            if (l > 0) prv = *(const u16x8*)&qkvp[(tokb + l - 1) * 8192 + 2048 + h * DH + d];
            u16x8 outv;
            for (int u = 0; u < 8; u++) {
                float kc = bf2f(cur[u]);
                float kp = bf2f(prv[u]);
                outv[u] = f2bf((1.0f - s) * kc + s * kp);
            }
            *(u16x8*)&k_sm[(((size_t)bh) * L_SEQ + l) * DH + d] = outv;
        }
    }
}

// ---------------- flash attention + SiLU(p) gating (round-15 version, verified
// best: serial + swapped-operand QK^T + adt-shift + v_perm pack + max3 tree,
// K/V dbuf stage-ahead, XCD head-clustering. ~92.5 us measured.)
__global__ __launch_bounds__(256) void attn_kernel(const u16* __restrict__ qkvp,
                                                   const u16* __restrict__ k_sm,
                                                   const u16* __restrict__ v_t,
                                                   u16* __restrict__ ag2,
                                                   const float* __restrict__ log_scale) {
    __shared__ u16 k_s[16384];   // 2 bufs x [kt 0..3][jrow 0..63][32 k] (swizzled content)
    __shared__ u16 vt_s[16384];  // 2 bufs x [jt 0..1][d 0..127][32 j]  (swizzled content)
    __shared__ u16 p_s[4608];    // per-wave 16 x 72 (single buffer)
    int tid = threadIdx.x;
    // XCD clustering: lin%8 = XCD (round-robin dispatch); 4 heads per XCD.
    unsigned lin = blockIdx.x + 16u * blockIdx.y;
    unsigned xcd = lin & 7, tt = lin >> 3;
    int bh = (int)(xcd * 4 + (tt & 3));
    int pair = (int)(tt >> 2);
    int bb = bh >> 4, h = bh & 15;
    int w = tid >> 6, lane = tid & 63, quad = lane >> 4, ln = lane & 15;
    size_t tokb = (size_t)bb * L_SEQ;

    const float LOG2E = 1.44269504f;
    float inv = 1.0f / (__expf(2.0f * log_scale[h]) * sqrtf((float)DH));
    float scl = inv * LOG2E;
    float slope2 = ((h < 8) ? exp2f(-8.0f * (float)h / 7.0f) : 0.0f) * LOG2E;

    int lrow = lane >> 2, lcol = lane & 3;
    int lsw8 = (lcol ^ ((lrow >> 1) & 3)) * 8;  // write-side swizzle via global source addr
    int qsw = (quad ^ ((ln >> 1) & 3)) * 8;     // read-side swizzle (same involution)
    f32x4 zero4 = {0.f, 0.f, 0.f, 0.f};
    u16* pw = &p_s[w * 1152];
    const short ONE_BF = (short)0x3F80;
    bf16x8 ones = {ONE_BF, ONE_BF, ONE_BF, ONE_BF, ONE_BF, ONE_BF, ONE_BF, ONE_BF};

    for (int sidx = 0; sidx < 2; sidx++) {
        int ib = sidx == 0 ? (31 - pair) : pair;
        int i0 = ib * 64;
        int si = i0 + w * 16;
        int iq = si + ln;          // this lane's q-row (swapped layout)

        // Q fragments straight from global (same data serves as B-operand now)
        bf16x8 qf[4];
        for (int kt = 0; kt < 4; kt++)
            qf[kt] = *(const bf16x8*)&qkvp[(tokb + si + ln) * 8192 + h * DH + kt * 32 + quad * 8];

        // shifted-domain running max: m_true(t) = mshift(t) + slope2*j0(t)
        float mshift = -1e30f;
        float astep = slope2 * 64.0f;
        f32x4 o_acc[8], l_acc;
        for (int dt = 0; dt < 8; dt++) o_acc[dt] = zero4;
        l_acc = zero4;

        // FIXED ALiBi base table (no per-iter increment)
        float adt0[4][4];
        for (int ct = 0; ct < 4; ct++)
            for (int r = 0; r < 4; r++)
                adt0[ct][r] = slope2 * (float)(ct * 16 + quad * 4 + r);

        // staging pointers: advance by constant per j-tile (pre-swizzled source)
        const u16* kg[4];
        for (int g = 0; g < 4; g++)
            kg[g] = k_sm + ((size_t)bh * L_SEQ + g * 16 + lrow) * DH + w * 32 + lsw8;
        const u16* vg[4];
        int vloff[4];
        for (int q = 0; q < 4; q++) {
            int c = w * 4 + q;
            int jt = c >> 3, dg = c & 7;
            vg[q] = v_t + ((size_t)bh * DH + dg * 16 + lrow) * L_SEQ + jt * 32 + lsw8;
            vloff[q] = jt * 4096 + dg * 512;
        }

        // prologue: stage j-tile 0 into buffer 0
        for (int g = 0; g < 4; g++) { gl_lds16(kg[g], &k_s[w * 2048 + g * 512]); kg[g] += 64 * DH; }
        for (int q = 0; q < 4; q++) { gl_lds16(vg[q], &vt_s[vloff[q]]); vg[q] += 64; }
        __syncthreads();

        int cur = 0;
        for (int j0 = 0; j0 <= i0; j0 += 64) {
            // stage NEXT tile into the other buffer; in flight across compute
            if (j0 + 64 <= i0) {
                int nb = (cur ^ 1) * 8192;
                for (int g = 0; g < 4; g++) { gl_lds16(kg[g], &k_s[nb + w * 2048 + g * 512]); kg[g] += 64 * DH; }
                for (int q = 0; q < 4; q++) { gl_lds16(vg[q], &vt_s[nb + vloff[q]]); vg[q] += 64; }
            }
            const u16* kb = &k_s[cur * 8192];
            const u16* vb = &vt_s[cur * 8192];

            // S^T = K Q^T: swapped operands. Lane: sc[ct][r] = S[si+ln][j0 + ct*16 + quad*4 + r]
            f32x4 sc[4];
            for (int ct = 0; ct < 4; ct++) sc[ct] = zero4;
            __builtin_amdgcn_s_setprio(1);
            for (int kt = 0; kt < 4; kt++)
                for (int ct = 0; ct < 4; ct++) {
                    bf16x8 bfr = *(const bf16x8*)&kb[kt * 2048 + (ct * 16 + ln) * 32 + qsw];
                    sc[ct] = __builtin_amdgcn_mfma_f32_16x16x32_bf16(bfr, qf[kt], sc[ct], 0, 0, 0);
                }
            __builtin_amdgcn_s_setprio(0);

            // shifted scores: s_true = s2 + slope2*j0 (uniform) -- never materialized
            bool full = (j0 + 63 <= si);
            float s2[4][4];
            for (int ct = 0; ct < 4; ct++)
                for (int r = 0; r < 4; r++) {
                    float v = fmaf(sc[ct][r], scl, adt0[ct][r]);
                    if (!full) {
                        int j = j0 + ct * 16 + quad * 4 + r;
                        if (j > iq) v = -3.0e38f;
                    }
                    s2[ct][r] = v;
                }
            // row max in shifted domain: max3-shaped tree + cross-quad reduce
            float x0 = fmaxf(fmaxf(s2[0][0], s2[0][1]), s2[0][2]);
            float x1 = fmaxf(fmaxf(s2[0][3], s2[1][0]), s2[1][1]);
            float x2 = fmaxf(fmaxf(s2[1][2], s2[1][3]), s2[2][0]);
            float x3 = fmaxf(fmaxf(s2[2][1], s2[2][2]), s2[2][3]);
            float x4 = fmaxf(fmaxf(s2[3][0], s2[3][1]), s2[3][2]);
            float y0 = fmaxf(fmaxf(x0, x1), x2);
            float y1 = fmaxf(fmaxf(x3, x4), s2[3][3]);
            float mr = fmaxf(y0, y1);
            mr = fmaxf(mr, __shfl_xor(mr, 16));
            mr = fmaxf(mr, __shfl_xor(mr, 32));
            // shifted-domain update: m_old_shift(this iter) = mshift - astep
            float msh_old = mshift - astep;
            float mnew = fmaxf(msh_old, mr);
            float alpha = exp2f(msh_old - mnew);
            mshift = mnew;

            // P: exp2 in shifted domain, v_perm pack, 4x ds_write_b64
            for (int ct = 0; ct < 4; ct++) {
                float p0 = exp2f(s2[ct][0] - mnew);
                float p1 = exp2f(s2[ct][1] - mnew);
                float p2 = exp2f(s2[ct][2] - mnew);
                float p3 = exp2f(s2[ct][3] - mnew);
                unsigned d0 = __builtin_amdgcn_perm(__float_as_uint(p1), __float_as_uint(p0), 0x07060302u);
                unsigned d1 = __builtin_amdgcn_perm(__float_as_uint(p3), __float_as_uint(p2), 0x07060302u);
                uint2 dd; dd.x = d0; dd.y = d1;
                *(uint2*)&pw[ln * 72 + ct * 16 + quad * 4] = dd;
            }

            // rescale O/l: gather alpha for rows quad*4+e from lanes (quad*16)+(quad*4+e)
            if (__any(alpha != 1.0f)) {
                float av[4];
                for (int e = 0; e < 4; e++) av[e] = __shfl(alpha, quad * 20 + e);
                for (int dt = 0; dt < 8; dt++) {
                    f32x4 o = o_acc[dt];
                    for (int e = 0; e < 4; e++) o[e] *= av[e];
                    o_acc[dt] = o;
                }
                for (int e = 0; e < 4; e++) l_acc[e] *= av[e];
            }
            asm volatile("s_waitcnt lgkmcnt(0)" ::: "memory");
            __builtin_amdgcn_s_setprio(1);
            for (int ks = 0; ks < 2; ks++) {
                bf16x8 pa = *(const bf16x8*)&pw[ln * 72 + ks * 32 + quad * 8];
                l_acc = __builtin_amdgcn_mfma_f32_16x16x32_bf16(pa, ones, l_acc, 0, 0, 0);
                for (int dt = 0; dt < 8; dt++) {
                    bf16x8 vf = *(const bf16x8*)&vb[ks * 4096 + (dt * 16 + ln) * 32 + qsw];
                    o_acc[dt] = __builtin_amdgcn_mfma_f32_16x16x32_bf16(pa, vf, o_acc[dt], 0, 0, 0);
                }
            }
            __builtin_amdgcn_s_setprio(0);
            __syncthreads();
            cur ^= 1;
        }

        // epilogue: normalize (rcp), SiLU(p) gate (exp2+rcp), store bf16
        float rinv[4];
        for (int r = 0; r < 4; r++) rinv[r] = __builtin_amdgcn_rcpf(l_acc[r]);
        for (int dt = 0; dt < 8; dt++)
            for (int r = 0; r < 4; r++) {
                int i = si + quad * 4 + r;
                int dcol = dt * 16 + ln;
                float o = o_acc[dt][r] * rinv[r];
                float pv = bf2f(qkvp[(tokb + i) * 8192 + 6144 + h * DH + dcol]);
                float gate = pv * __builtin_amdgcn_rcpf(1.0f + exp2f(-pv * LOG2E));
                ag2[(tokb + i) * 2048 + h * DH + dcol] = f2bf(gate * o);
            }
    }
}

extern "C" void kernel_launch(void* const* d_in, const int* in_sizes, int n_in,
                              void* d_out, int out_size, void* d_ws, size_t ws_size,
                              hipStream_t stream) {
    const float* x       = (const float*)d_in[0];
    const float* ln1_g   = (const float*)d_in[1];
    const float* ln1_b   = (const float*)d_in[2];
    const float* ln2_g   = (const float*)d_in[3];
    const float* ln2_b   = (const float*)d_in[4];
    const float* w_in    = (const float*)d_in[5];
    const float* w_out   = (const float*)d_in[6];
    const float* smear_f = (const float*)d_in[7];
    const float* logsc   = (const float*)d_in[8];
    float* out = (float*)d_out;
    char* ws = (char*)d_ws;

    // ws layout (bytes)
    u16* w_inT   = (u16*)(ws + 0);                       // 16 MB  [8192,1024]
    u16* w_outT  = (u16*)(ws + (size_t)16777216);        //  4 MB  [1024,2048]
    u16* lnA     = (u16*)(ws + (size_t)20971520);        //  8 MB  [4096,1024]
    u16* qkvp    = (u16*)(ws + (size_t)29360128);        // 64 MB  [4096,8192]
    u16* k_sm    = (u16*)(ws + (size_t)96468992);        // 16 MB  [bh][l][128]
    u16* ag2     = (u16*)(ws + (size_t)113246208);       // 16 MB  [4096,2048]
    float* out_pre = (float*)(ws + (size_t)96468992);    // alias k_sm (dead after attn)
    u16* v_t     = (u16*)(ws + 0);                       // alias w_inT (dead after gemm1)

    dim3 b32x8(32, 8);
    conv_transpose<<<dim3(8192 / 32, 1024 / 64), b32x8, 0, stream>>>(w_in, w_inT, 1024, 8192);
    conv_transpose<<<dim3(1024 / 32, 2048 / 64), b32x8, 0, stream>>>(w_out, w_outT, 2048, 1024);
    ln_fwd<<<NTOK, 256, 0, stream>>>(x, ln1_g, ln1_b, (void*)lnA, 1);
    gemm_8ph<<<dim3(8192 / 256, 4096 / 256), 512, 0, stream>>>(lnA, w_inT, qkvp, NTOK, 8192, 1024);
    vT_smear<<<dim3(L_SEQ / 64, 5, 32), b32x8, 0, stream>>>(qkvp, smear_f, v_t, k_sm);
    attn_kernel<<<dim3(16, 32), 256, 0, stream>>>(qkvp, k_sm, v_t, ag2, logsc);
    gemm_bt64<<<dim3(1024 / 128, 4096 / 64), 256, 0, stream>>>(ag2, w_outT, out_pre, NTOK, 1024, 2048);
    ln_fwd<<<NTOK, 256, 0, stream>>>(out_pre, ln2_g, ln2_b, (void*)out, 0);
}